// Round 13
// baseline (521.474 us; speedup 1.0000x reference)
//
#include <hip/hip_runtime.h>
#include <hip/hip_bf16.h>
#include <hip/hip_fp16.h>
#include <hip/hip_cooperative_groups.h>

namespace cg = cooperative_groups;

#define NN 25000
#define NE 100000
#define FIN 32
#define DD 64
#define NG 1000

typedef unsigned short u16;
typedef __attribute__((ext_vector_type(8))) short short8;
typedef __attribute__((ext_vector_type(8))) _Float16 f16x8;
typedef __attribute__((ext_vector_type(4))) float f32x4;

__device__ __forceinline__ u16 f2h(float f) {
    __half h = __float2half(f);
    return __builtin_bit_cast(u16, h);
}
__device__ __forceinline__ float h2f(u16 u) {
    __half h = __builtin_bit_cast(__half, u);
    return __half2float(h);
}
__device__ __forceinline__ f16x8 s2h(short8 v) { return __builtin_bit_cast(f16x8, v); }
// edge_index may be int64 read as int32 words: odd words would all be 0.
__device__ __forceinline__ bool idx_is_i64(const int* e) {
    return (e[1] == 0) & (e[3] == 0) & (e[5] == 0) & (e[7] == 0) & (e[9] == 0);
}
__device__ __forceinline__ int ld_src(const int* e, int i, bool i64) {
    return i64 ? e[2 * i] : e[i];
}
__device__ __forceinline__ int ld_dst(const int* e, int i, bool i64) {
    return i64 ? e[2 * (NE + i)] : e[NE + i];
}

// =========================================================================================
// Megakernel phases as __noinline__ functions: independent register allocation per phase
// (round-12's monolithic body spilled: FETCH 105MB / WRITE 216MB). Dynamic extern-shared
// keeps LDS pointers in addrspace(3) so accesses stay ds_* ops.
// =========================================================================================

__device__ __noinline__ void phase_pre(
    const float* __restrict__ x, const float* __restrict__ W0, const float* __restrict__ b0,
    u16* __restrict__ x1b, const float* __restrict__ We2, const float* __restrict__ be2,
    float* __restrict__ agg, float* __restrict__ pooled, u16* __restrict__ Bt2,
    const float* __restrict__ Wi, const float* __restrict__ Wh, const float* __restrict__ Wroot,
    u16* __restrict__ Wib, u16* __restrict__ Whb, u16* __restrict__ Wrb,
    const float* __restrict__ W11, const float* __restrict__ W12,
    const float* __restrict__ W21, const float* __restrict__ W22,
    u16* __restrict__ W11b, u16* __restrict__ W12b,
    u16* __restrict__ W21b, u16* __restrict__ W22b, int bid, int G) {
    extern __shared__ char smemraw[];
    float* sbuf = (float*)smemraw;
    const int tid = threadIdx.x;
    const int lane = tid & 63;
    for (int vb = bid; vb < 1628; vb += G) {
        __syncthreads();
        if (vb < 1563) {
            float* sW = sbuf;           // [FIN*DD] = 2048
            float* sx = sbuf + 2048;    // [16*FIN] = 512
            for (int i = tid; i < FIN * DD; i += 512) sW[i] = W0[i];
            int nbase = vb * 16;
            for (int i = tid; i < 16 * FIN; i += 512) {
                int nl = i >> 5, f = i & 31;
                int n = nbase + nl;
                sx[i] = (n < NN) ? x[n * FIN + f] : 0.f;
            }
            __syncthreads();
            int nl8 = tid >> 6;   // 0..7, 2 rows each
            float bias = b0[lane];
            #pragma unroll
            for (int rr = 0; rr < 2; rr++) {
                int row = nl8 * 2 + rr;
                int n = nbase + row;
                if (n < NN) {
                    float acc = bias;
                    #pragma unroll
                    for (int f = 0; f < FIN; f++) acc += sx[row * FIN + f] * sW[f * DD + lane];
                    x1b[n * DD + lane] = f2h(fmaxf(acc, 0.f));
                }
            }
        } else {
            int kc = vb - 1563;                 // [0,65)
            const float* src = (kc < 64) ? (We2 + kc * 4096) : be2;
            for (int i = tid; i < 4096; i += 512) sbuf[i] = src[i];
            __syncthreads();
            for (int m = tid; m < 4096; m += 512) {
                int f = m >> 9, ln = (m >> 3) & 63, j = m & 7;
                int s = f >> 2, c = f & 3;
                int o = c * 16 + (ln & 15);
                int rlow = s * 32 + (ln >> 4) * 8 + j;
                Bt2[kc * 4096 + m] = f2h(sbuf[rlow * 64 + o]);
            }
        }
    }
    int gt = bid * 512 + tid;
    int STR = G * 512;
    for (int i = gt; i < NN * DD; i += STR) agg[i] = 0.f;
    for (int i = gt; i < NG * DD; i += STR) pooled[i] = 0.f;
    for (int i = gt; i < 12288; i += STR) {
        int fr = i >> 9, ln = (i >> 3) & 63, j = i & 7;
        int c = fr >> 1, kcx = fr & 1;
        int row = c * 16 + (ln & 15);
        int col = kcx * 32 + (ln >> 4) * 8 + j;
        Wib[i] = f2h(Wi[row * 64 + col]);
        Whb[i] = f2h(Wh[row * 64 + col]);
    }
    for (int i = gt; i < 4096; i += STR) {
        int fr = i >> 9, ln = (i >> 3) & 63, j = i & 7;
        int c = fr >> 1, kcx = fr & 1;
        int row = c * 16 + (ln & 15);
        int col = kcx * 32 + (ln >> 4) * 8 + j;
        int idx = col * 64 + row;
        Wrb[i]  = f2h(Wroot[idx]);
        W11b[i] = f2h(W11[idx]);
        W12b[i] = f2h(W12[idx]);
        W21b[i] = f2h(W21[idx]);
        W22b[i] = f2h(W22[idx]);
    }
}

__device__ __noinline__ void phase_msg(
    const float* __restrict__ ea, const int* __restrict__ eidx,
    const float* __restrict__ We1, const float* __restrict__ be1,
    const u16* __restrict__ x1b, const u16* __restrict__ Bt2,
    float* __restrict__ agg, int bid, int G) {
    extern __shared__ char smemraw[];
    u16* sX    = (u16*)smemraw;            // 18432 B
    u16* sTh   = (u16*)(smemraw + 18432);  // 16768 B
    float* sWe1 = (float*)(smemraw + 35200);
    float* sbe1 = (float*)(smemraw + 37248);
    int* sDst  = (int*)(smemraw + 37504);
    const int tid = threadIdx.x;
    const int lane = tid & 63, wv = tid >> 6;
    const int ll = lane & 15, quad = lane >> 4;
    const int rh = wv >> 2, cq = wv & 3;
    const bool i64 = idx_is_i64(eidx);
    const f32x4 zero = (f32x4){0.f, 0.f, 0.f, 0.f};

    for (int vt = bid; vt < 782; vt += G) {
        __syncthreads();
        const int e0 = vt * 128;
        sWe1[tid] = We1[tid];
        if (tid < 64) sbe1[tid] = be1[tid];
        if (tid < 128) {
            sDst[tid] = (e0 + tid < NE) ? ld_dst(eidx, e0 + tid, i64) : 0;
            sTh[64 * 128 + tid] = 0x3C00;
        }
        const int el4 = tid >> 2, seg = tid & 3;
        const int eg4 = e0 + el4;
        {
            if (eg4 < NE) {
                int sv = ld_src(eidx, eg4, i64);
                const u16* xr = x1b + sv * 64 + seg * 16;
                *(uint4*)&sX[el4 * 72 + seg * 16]     = *(const uint4*)(xr);
                *(uint4*)&sX[el4 * 72 + seg * 16 + 8] = *(const uint4*)(xr + 8);
            } else {
                uint4 z = make_uint4(0, 0, 0, 0);
                *(uint4*)&sX[el4 * 72 + seg * 16]     = z;
                *(uint4*)&sX[el4 * 72 + seg * 16 + 8] = z;
            }
        }
        float eav[8];
        if (eg4 < NE) {
            f32x4 v0 = *(const f32x4*)(ea + eg4 * 8);
            f32x4 v1 = *(const f32x4*)(ea + eg4 * 8 + 4);
            #pragma unroll
            for (int f = 0; f < 4; f++) { eav[f] = v0[f]; eav[4 + f] = v1[f]; }
        } else {
            #pragma unroll
            for (int f = 0; f < 8; f++) eav[f] = 0.f;
        }
        __syncthreads();
        {
            int k0 = seg * 16;
            for (int kk = 0; kk < 16; kk++) {
                int k = k0 + kk;
                float acc = sbe1[k];
                #pragma unroll
                for (int f = 0; f < 8; f++) acc += eav[f] * sWe1[f * 64 + k];
                sTh[k * 128 + el4] = f2h((eg4 < NE) ? fmaxf(acc, 0.f) : 0.f);
            }
        }
        __syncthreads();

        short8 xa[4][2];
        #pragma unroll
        for (int rt = 0; rt < 4; rt++)
            #pragma unroll
            for (int s = 0; s < 2; s++)
                xa[rt][s] = *(const short8*)&sX[(rh * 64 + rt * 16 + ll) * 72 + s * 32 + quad * 8];

        f32x4 msg[4];
        #pragma unroll
        for (int rt = 0; rt < 4; rt++) msg[rt] = zero;

        const u16* gB0 = Bt2 + (0 * 4 + cq) * 512 + lane * 8;
        const u16* gB1 = Bt2 + (1 * 4 + cq) * 512 + lane * 8;
        const int tkoff = rh * 64 + quad * 4;

        #define LDR(dst, kcv, rtv) dst = *(const uint2*)&sTh[(kcv) * 128 + tkoff + (rtv) * 16];
        #define CVT(t, raw)                                                      \
            {                                                                    \
                __half2 _a = __builtin_bit_cast(__half2, (raw).x);               \
                __half2 _b = __builtin_bit_cast(__half2, (raw).y);               \
                float2 _fa = __half22float2(_a);                                 \
                float2 _fb = __half22float2(_b);                                 \
                t = (f32x4){_fa.x, _fa.y, _fb.x, _fb.y};                         \
            }

        short8 c00 = *(const short8*)(gB0);
        short8 c01 = *(const short8*)(gB1);
        short8 c10 = *(const short8*)(gB0 + 4096);
        short8 c11 = *(const short8*)(gB1 + 4096);
        uint2 tkA[4], tkB[4];
        #pragma unroll
        for (int rt = 0; rt < 4; rt++) LDR(tkA[rt], 0, rt);

        for (int kc = 0; kc < 62; kc += 2) {
            short8 n00 = *(const short8*)(gB0 + (kc + 2) * 4096);
            short8 n01 = *(const short8*)(gB1 + (kc + 2) * 4096);
            short8 n10 = *(const short8*)(gB0 + (kc + 3) * 4096);
            short8 n11 = *(const short8*)(gB1 + (kc + 3) * 4096);
            #pragma unroll
            for (int rt = 0; rt < 4; rt++) LDR(tkB[rt], kc + 1, rt);
            #pragma unroll
            for (int rt = 0; rt < 4; rt++) {
                f32x4 q0 = __builtin_amdgcn_mfma_f32_16x16x32_f16(s2h(xa[rt][0]), s2h(c00), zero, 0, 0, 0);
                f32x4 q1 = __builtin_amdgcn_mfma_f32_16x16x32_f16(s2h(xa[rt][1]), s2h(c01), zero, 0, 0, 0);
                f32x4 t; CVT(t, tkA[rt]);
                msg[rt] += t * q0;
                msg[rt] += t * q1;
            }
            #pragma unroll
            for (int rt = 0; rt < 4; rt++) LDR(tkA[rt], kc + 2, rt);
            #pragma unroll
            for (int rt = 0; rt < 4; rt++) {
                f32x4 q0 = __builtin_amdgcn_mfma_f32_16x16x32_f16(s2h(xa[rt][0]), s2h(c10), zero, 0, 0, 0);
                f32x4 q1 = __builtin_amdgcn_mfma_f32_16x16x32_f16(s2h(xa[rt][1]), s2h(c11), zero, 0, 0, 0);
                f32x4 t; CVT(t, tkB[rt]);
                msg[rt] += t * q0;
                msg[rt] += t * q1;
            }
            c00 = n00; c01 = n01; c10 = n10; c11 = n11;
        }
        {
            short8 n00 = *(const short8*)(gB0 + 64 * 4096);
            short8 n01 = *(const short8*)(gB1 + 64 * 4096);
            #pragma unroll
            for (int rt = 0; rt < 4; rt++) LDR(tkB[rt], 63, rt);
            #pragma unroll
            for (int rt = 0; rt < 4; rt++) {
                f32x4 q0 = __builtin_amdgcn_mfma_f32_16x16x32_f16(s2h(xa[rt][0]), s2h(c00), zero, 0, 0, 0);
                f32x4 q1 = __builtin_amdgcn_mfma_f32_16x16x32_f16(s2h(xa[rt][1]), s2h(c01), zero, 0, 0, 0);
                f32x4 t; CVT(t, tkA[rt]);
                msg[rt] += t * q0;
                msg[rt] += t * q1;
            }
            #pragma unroll
            for (int rt = 0; rt < 4; rt++) LDR(tkA[rt], 64, rt);
            #pragma unroll
            for (int rt = 0; rt < 4; rt++) {
                f32x4 q0 = __builtin_amdgcn_mfma_f32_16x16x32_f16(s2h(xa[rt][0]), s2h(c10), zero, 0, 0, 0);
                f32x4 q1 = __builtin_amdgcn_mfma_f32_16x16x32_f16(s2h(xa[rt][1]), s2h(c11), zero, 0, 0, 0);
                f32x4 t; CVT(t, tkB[rt]);
                msg[rt] += t * q0;
                msg[rt] += t * q1;
            }
            #pragma unroll
            for (int rt = 0; rt < 4; rt++) {
                f32x4 q0 = __builtin_amdgcn_mfma_f32_16x16x32_f16(s2h(xa[rt][0]), s2h(n00), zero, 0, 0, 0);
                f32x4 q1 = __builtin_amdgcn_mfma_f32_16x16x32_f16(s2h(xa[rt][1]), s2h(n01), zero, 0, 0, 0);
                f32x4 t; CVT(t, tkA[rt]);
                msg[rt] += t * q0;
                msg[rt] += t * q1;
            }
        }
        #undef LDR
        #undef CVT

        #pragma unroll
        for (int rt = 0; rt < 4; rt++) {
            #pragma unroll
            for (int r = 0; r < 4; r++) {
                int el = rh * 64 + rt * 16 + quad * 4 + r;
                int eg = e0 + el;
                if (eg < NE) {
                    int d = sDst[el];
                    atomicAdd(&agg[d * 64 + cq * 16 + ll], msg[rt][r]);
                }
            }
        }
    }
}

__device__ __noinline__ void phase_gru(
    const u16* __restrict__ x1b, const float* __restrict__ agg,
    const u16* __restrict__ Wib, const u16* __restrict__ Whb, const u16* __restrict__ Wrb,
    const float* __restrict__ bconv, const float* __restrict__ bi, const float* __restrict__ bh,
    const int* __restrict__ batch, float* __restrict__ pooled, int bid, int G) {
    extern __shared__ char smemraw[];
    u16* sX2 = (u16*)smemraw;              // 9216 B
    float* hb = (float*)(smemraw + 9216);  // 16640 B
    int* sBatch = (int*)(smemraw + 25856); // 256 B
    const int tid = threadIdx.x;
    const int lane = tid & 63, ll = lane & 15, quad = lane >> 4;
    const f32x4 zero = (f32x4){0.f, 0.f, 0.f, 0.f};
    for (int vt = bid; vt < 391; vt += G) {
        __syncthreads();
        const bool act = tid < 256;
        const int n0 = vt * 64;
        const int wv = (tid >> 6) & 3;
        short8 ha[2];
        float hnv[4][4];
        if (act) {
            if (tid < 64) {
                int n = n0 + tid;
                sBatch[tid] = (n < NN) ? batch[n] : -1;
            }
            int n = n0 + wv * 16 + ll;
            #pragma unroll
            for (int kc = 0; kc < 2; kc++) {
                if (n < NN) ha[kc] = *(const short8*)(x1b + n * 64 + kc * 32 + quad * 8);
                else        ha[kc] = (short8){0,0,0,0,0,0,0,0};
            }
            f32x4 acc1[4];
            #pragma unroll
            for (int c = 0; c < 4; c++) acc1[c] = zero;
            #pragma unroll
            for (int kc = 0; kc < 2; kc++) {
                #pragma unroll
                for (int c = 0; c < 4; c++) {
                    short8 b = *(const short8*)&Wrb[(c * 2 + kc) * 512 + lane * 8];
                    acc1[c] = __builtin_amdgcn_mfma_f32_16x16x32_f16(s2h(ha[kc]), s2h(b), acc1[c], 0, 0, 0);
                }
            }
            #pragma unroll
            for (int c = 0; c < 4; c++) {
                int col = c * 16 + ll;
                float bcv = bconv[col];
                #pragma unroll
                for (int r = 0; r < 4; r++) {
                    int row = wv * 16 + quad * 4 + r;
                    int n2 = n0 + row;
                    float v = 0.f;
                    if (n2 < NN) v = fmaxf(acc1[c][r] + agg[n2 * 64 + col] + bcv, 0.f);
                    sX2[row * 72 + col] = f2h(v);
                }
            }
        }
        __syncthreads();
        if (act) {
            short8 xg[2];
            #pragma unroll
            for (int kc = 0; kc < 2; kc++)
                xg[kc] = *(const short8*)&sX2[(wv * 16 + ll) * 72 + kc * 32 + quad * 8];
            f32x4 agi[12], agh[12];
            #pragma unroll
            for (int c = 0; c < 12; c++) { agi[c] = zero; agh[c] = zero; }
            #pragma unroll
            for (int kc = 0; kc < 2; kc++) {
                #pragma unroll
                for (int c = 0; c < 12; c++) {
                    short8 bi8 = *(const short8*)&Wib[(c * 2 + kc) * 512 + lane * 8];
                    short8 bh8 = *(const short8*)&Whb[(c * 2 + kc) * 512 + lane * 8];
                    agi[c] = __builtin_amdgcn_mfma_f32_16x16x32_f16(s2h(xg[kc]), s2h(bi8), agi[c], 0, 0, 0);
                    agh[c] = __builtin_amdgcn_mfma_f32_16x16x32_f16(s2h(ha[kc]), s2h(bh8), agh[c], 0, 0, 0);
                }
            }
            #pragma unroll
            for (int c0 = 0; c0 < 4; c0++) {
                int d = c0 * 16 + ll;
                float bir = bi[d],        bhr = bh[d];
                float biz = bi[64 + d],   bhz = bh[64 + d];
                float bin = bi[128 + d],  bhn = bh[128 + d];
                #pragma unroll
                for (int r = 0; r < 4; r++) {
                    int row = wv * 16 + quad * 4 + r;
                    int n2 = n0 + row;
                    float gir = agi[c0][r] + bir,     ghr = agh[c0][r] + bhr;
                    float giz = agi[c0 + 4][r] + biz, ghz = agh[c0 + 4][r] + bhz;
                    float gin = agi[c0 + 8][r] + bin, ghn = agh[c0 + 8][r] + bhn;
                    float rg = __fdividef(1.f, 1.f + __expf(-(gir + ghr)));
                    float zg = __fdividef(1.f, 1.f + __expf(-(giz + ghz)));
                    float xt = gin + rg * ghn;
                    float e2 = __expf(2.f * xt);
                    float ng = 1.f - __fdividef(2.f, e2 + 1.f);
                    float hv = (n2 < NN) ? h2f(x1b[n2 * 64 + d]) : 0.f;
                    hnv[c0][r] = (n2 < NN) ? ((1.f - zg) * ng + zg * hv) : 0.f;
                }
            }
        }
        __syncthreads();
        if (act) {
            #pragma unroll
            for (int c0 = 0; c0 < 4; c0++) {
                int d = c0 * 16 + ll;
                #pragma unroll
                for (int r = 0; r < 4; r++) {
                    int row = wv * 16 + quad * 4 + r;
                    hb[row * 65 + d] = hnv[c0][r];
                }
            }
        }
        __syncthreads();
        if (act) {
            int d = lane;
            float sum = 0.f;
            int pb = sBatch[wv * 16];
            #pragma unroll
            for (int rr = 0; rr < 16; rr++) {
                int row = wv * 16 + rr;
                int b = sBatch[row];
                float v = hb[row * 65 + d];
                if (b != pb) {
                    if (pb >= 0) atomicAdd(&pooled[pb * 64 + d], sum);
                    sum = v; pb = b;
                } else {
                    sum += v;
                }
            }
            if (pb >= 0) atomicAdd(&pooled[pb * 64 + d], sum);
        }
    }
}

__device__ __noinline__ void phase_heads(
    const float* __restrict__ pooled,
    const u16* __restrict__ W11b, const float* __restrict__ b11,
    const u16* __restrict__ W12b, const float* __restrict__ b12,
    const float* __restrict__ W13, const float* __restrict__ b13,
    const u16* __restrict__ W21b, const float* __restrict__ b21,
    const u16* __restrict__ W22b, const float* __restrict__ b22,
    const float* __restrict__ W23, const float* __restrict__ b23,
    float* __restrict__ out, int bid, int G) {
    extern __shared__ char smemraw[];
    u16* sY = (u16*)smemraw;   // 9216 B
    const int tid = threadIdx.x;
    const int lane = tid & 63, ll = lane & 15, quad = lane >> 4;
    const f32x4 zero = (f32x4){0.f, 0.f, 0.f, 0.f};
    const u16* W1s[2] = {W11b, W21b}; const float* b1s[2] = {b11, b21};
    const u16* W2s[2] = {W12b, W22b}; const float* b2s[2] = {b12, b22};
    const float* W3s[2] = {W13, W23}; const float* b3s[2] = {b13, b23};
    for (int vt = bid; vt < 16; vt += G) {
        __syncthreads();
        const bool act = tid < 256;
        const int wv = (tid >> 6) & 3;
        const int g0 = vt * 64;
        short8 pa[2];
        if (act) {
            int g = g0 + wv * 16 + ll;
            #pragma unroll
            for (int kc = 0; kc < 2; kc++) {
                if (g < NG) {
                    const float* pr = pooled + g * 64 + kc * 32 + quad * 8;
                    f32x4 v0 = *(const f32x4*)(pr);
                    f32x4 v1 = *(const f32x4*)(pr + 4);
                    short8 s;
                    #pragma unroll
                    for (int j = 0; j < 4; j++) {
                        s[j]     = (short)f2h(v0[j]);
                        s[4 + j] = (short)f2h(v1[j]);
                    }
                    pa[kc] = s;
                } else {
                    pa[kc] = (short8){0,0,0,0,0,0,0,0};
                }
            }
        }
        for (int hd = 0; hd < 2; hd++) {
            if (act) {
                f32x4 a1[4];
                #pragma unroll
                for (int c = 0; c < 4; c++) a1[c] = zero;
                #pragma unroll
                for (int kc = 0; kc < 2; kc++)
                    #pragma unroll
                    for (int c = 0; c < 4; c++) {
                        short8 b = *(const short8*)&W1s[hd][(c * 2 + kc) * 512 + lane * 8];
                        a1[c] = __builtin_amdgcn_mfma_f32_16x16x32_f16(s2h(pa[kc]), s2h(b), a1[c], 0, 0, 0);
                    }
                #pragma unroll
                for (int c = 0; c < 4; c++) {
                    int col = c * 16 + ll;
                    float bv = b1s[hd][col];
                    #pragma unroll
                    for (int r = 0; r < 4; r++) {
                        int row = wv * 16 + quad * 4 + r;
                        sY[row * 72 + col] = f2h(fmaxf(a1[c][r] + bv, 0.f));
                    }
                }
            }
            __syncthreads();
            if (act) {
                short8 ya[2];
                #pragma unroll
                for (int kc = 0; kc < 2; kc++)
                    ya[kc] = *(const short8*)&sY[(wv * 16 + ll) * 72 + kc * 32 + quad * 8];
                f32x4 a2[4];
                #pragma unroll
                for (int c = 0; c < 4; c++) a2[c] = zero;
                #pragma unroll
                for (int kc = 0; kc < 2; kc++)
                    #pragma unroll
                    for (int c = 0; c < 4; c++) {
                        short8 b = *(const short8*)&W2s[hd][(c * 2 + kc) * 512 + lane * 8];
                        a2[c] = __builtin_amdgcn_mfma_f32_16x16x32_f16(s2h(ya[kc]), s2h(b), a2[c], 0, 0, 0);
                    }
                #pragma unroll
                for (int r = 0; r < 4; r++) {
                    float part = 0.f;
                    #pragma unroll
                    for (int c = 0; c < 4; c++) {
                        int col = c * 16 + ll;
                        part += fmaxf(a2[c][r] + b2s[hd][col], 0.f) * W3s[hd][col];
                    }
                    part += __shfl_xor(part, 1, 64);
                    part += __shfl_xor(part, 2, 64);
                    part += __shfl_xor(part, 4, 64);
                    part += __shfl_xor(part, 8, 64);
                    if (ll == 0) {
                        int g = g0 + wv * 16 + quad * 4 + r;
                        if (g < NG) out[g * 2 + hd] = part + b3s[hd][0];
                    }
                }
            }
            __syncthreads();
        }
    }
}

__global__ __launch_bounds__(512, 4) void k_mega(
    const float* __restrict__ x, const int* __restrict__ eidx,
    const float* __restrict__ ea, const int* __restrict__ batch,
    const float* __restrict__ W0, const float* __restrict__ b0,
    const float* __restrict__ We1, const float* __restrict__ be1,
    const float* __restrict__ We2, const float* __restrict__ be2,
    const float* __restrict__ Wroot, const float* __restrict__ bconv,
    const float* __restrict__ Wi, const float* __restrict__ Wh,
    const float* __restrict__ bi, const float* __restrict__ bh,
    const float* __restrict__ W13, const float* __restrict__ b13,
    const float* __restrict__ W23, const float* __restrict__ b23,
    const float* __restrict__ b11, const float* __restrict__ b12,
    const float* __restrict__ b21, const float* __restrict__ b22,
    const float* __restrict__ W11, const float* __restrict__ W12,
    const float* __restrict__ W21, const float* __restrict__ W22,
    float* __restrict__ out,
    float* __restrict__ agg, u16* __restrict__ x1b, u16* __restrict__ Bt2,
    float* __restrict__ pooled,
    u16* __restrict__ Wib, u16* __restrict__ Whb, u16* __restrict__ Wrb,
    u16* __restrict__ W11b, u16* __restrict__ W12b,
    u16* __restrict__ W21b, u16* __restrict__ W22b) {
    cg::grid_group grid = cg::this_grid();
    const int bid = blockIdx.x;
    const int G = gridDim.x;
    phase_pre(x, W0, b0, x1b, We2, be2, agg, pooled, Bt2, Wi, Wh, Wroot,
              Wib, Whb, Wrb, W11, W12, W21, W22, W11b, W12b, W21b, W22b, bid, G);
    grid.sync();
    phase_msg(ea, eidx, We1, be1, x1b, Bt2, agg, bid, G);
    grid.sync();
    phase_gru(x1b, agg, Wib, Whb, Wrb, bconv, bi, bh, batch, pooled, bid, G);
    grid.sync();
    phase_heads(pooled, W11b, b11, W12b, b12, W13, b13, W21b, b21, W22b, b22,
                W23, b23, out, bid, G);
}

// =========================================================================================
// Classic 4-kernel fallback (round-11 verbatim, 225.6us) — used if cooperative launch fails.
// =========================================================================================
__global__ __launch_bounds__(256) void k_pre(const float* __restrict__ x,
                                             const float* __restrict__ W0,
                                             const float* __restrict__ b0,
                                             u16* __restrict__ x1b,
                                             const float* __restrict__ We2,
                                             const float* __restrict__ be2,
                                             float* __restrict__ agg,
                                             float* __restrict__ pooled,
                                             u16* __restrict__ Bt2,
                                             const float* __restrict__ Wi,
                                             const float* __restrict__ Wh,
                                             const float* __restrict__ Wroot,
                                             u16* __restrict__ Wib,
                                             u16* __restrict__ Whb,
                                             u16* __restrict__ Wrb,
                                             const float* __restrict__ W11,
                                             const float* __restrict__ W12,
                                             const float* __restrict__ W21,
                                             const float* __restrict__ W22,
                                             u16* __restrict__ W11b,
                                             u16* __restrict__ W12b,
                                             u16* __restrict__ W21b,
                                             u16* __restrict__ W22b) {
    __shared__ float sbuf[4096 + 512];
    int tid = threadIdx.x;
    if (blockIdx.x < 1563) {
        float* sW = sbuf;
        float* sx = sbuf + 4096;
        for (int i = tid; i < FIN * DD; i += 256) sW[i] = W0[i];
        int nbase = blockIdx.x * 16;
        for (int i = tid; i < 16 * FIN; i += 256) {
            int nl = i >> 5, f = i & 31;
            int n = nbase + nl;
            sx[i] = (n < NN) ? x[n * FIN + f] : 0.f;
        }
        __syncthreads();
        int lane = tid & 63, nl = tid >> 6;
        float bias = b0[lane];
        #pragma unroll
        for (int rr = 0; rr < 4; rr++) {
            int row = nl * 4 + rr;
            int n = nbase + row;
            if (n < NN) {
                float acc = bias;
                #pragma unroll
                for (int f = 0; f < FIN; f++) acc += sx[row * FIN + f] * sW[f * DD + lane];
                x1b[n * DD + lane] = f2h(fmaxf(acc, 0.f));
            }
        }
    } else if (blockIdx.x < 1628) {
        int kc = blockIdx.x - 1563;
        const float* src = (kc < 64) ? (We2 + kc * 4096) : be2;
        for (int i = tid; i < 4096; i += 256) sbuf[i] = src[i];
        __syncthreads();
        for (int m = tid; m < 4096; m += 256) {
            int f = m >> 9, ln = (m >> 3) & 63, j = m & 7;
            int s = f >> 2, c = f & 3;
            int o = c * 16 + (ln & 15);
            int rlow = s * 32 + (ln >> 4) * 8 + j;
            Bt2[kc * 4096 + m] = f2h(sbuf[rlow * 64 + o]);
        }
    } else {
        int tid0 = (blockIdx.x - 1628) * 256 + threadIdx.x;
        const int STR = 256 * 256;
        for (int i = tid0; i < NN * DD; i += STR) agg[i] = 0.f;
        for (int i = tid0; i < NG * DD; i += STR) pooled[i] = 0.f;
        for (int i = tid0; i < 12288; i += STR) {
            int fr = i >> 9, lane = (i >> 3) & 63, j = i & 7;
            int c = fr >> 1, kcx = fr & 1;
            int row = c * 16 + (lane & 15);
            int col = kcx * 32 + (lane >> 4) * 8 + j;
            Wib[i] = f2h(Wi[row * 64 + col]);
            Whb[i] = f2h(Wh[row * 64 + col]);
        }
        for (int i = tid0; i < 4096; i += STR) {
            int fr = i >> 9, lane = (i >> 3) & 63, j = i & 7;
            int c = fr >> 1, kcx = fr & 1;
            int row = c * 16 + (lane & 15);
            int col = kcx * 32 + (lane >> 4) * 8 + j;
            int idx = col * 64 + row;
            Wrb[i]  = f2h(Wroot[idx]);
            W11b[i] = f2h(W11[idx]);
            W12b[i] = f2h(W12[idx]);
            W21b[i] = f2h(W21[idx]);
            W22b[i] = f2h(W22[idx]);
        }
    }
}

__global__ __launch_bounds__(512, 4) void k_msg(const float* __restrict__ ea,
                                                const int* __restrict__ eidx,
                                                const float* __restrict__ We1,
                                                const float* __restrict__ be1,
                                                const u16* __restrict__ x1b,
                                                const u16* __restrict__ Bt2,
                                                float* __restrict__ agg) {
    __shared__ __align__(16) u16 sX[128 * 72];
    __shared__ __align__(16) u16 sTh[65 * 128 + 64];
    __shared__ float sWe1[8 * 64];
    __shared__ float sbe1[64];
    __shared__ int sDst[128];
    const int tid = threadIdx.x;
    const int lane = tid & 63, wv = tid >> 6;
    const int ll = lane & 15, quad = lane >> 4;
    const int rh = wv >> 2, cq = wv & 3;
    const int e0 = blockIdx.x * 128;
    const bool i64 = idx_is_i64(eidx);

    if (tid < 512) sWe1[tid] = We1[tid];
    if (tid < 64) sbe1[tid] = be1[tid];
    if (tid < 128) {
        sDst[tid] = (e0 + tid < NE) ? ld_dst(eidx, e0 + tid, i64) : 0;
        sTh[64 * 128 + tid] = 0x3C00;
    }
    const int el4 = tid >> 2, seg = tid & 3;
    const int eg4 = e0 + el4;
    {
        if (eg4 < NE) {
            int sv = ld_src(eidx, eg4, i64);
            const u16* xr = x1b + sv * 64 + seg * 16;
            *(uint4*)&sX[el4 * 72 + seg * 16]     = *(const uint4*)(xr);
            *(uint4*)&sX[el4 * 72 + seg * 16 + 8] = *(const uint4*)(xr + 8);
        } else {
            uint4 z = make_uint4(0, 0, 0, 0);
            *(uint4*)&sX[el4 * 72 + seg * 16]     = z;
            *(uint4*)&sX[el4 * 72 + seg * 16 + 8] = z;
        }
    }
    float eav[8];
    if (eg4 < NE) {
        f32x4 v0 = *(const f32x4*)(ea + eg4 * 8);
        f32x4 v1 = *(const f32x4*)(ea + eg4 * 8 + 4);
        #pragma unroll
        for (int f = 0; f < 4; f++) { eav[f] = v0[f]; eav[4 + f] = v1[f]; }
    } else {
        #pragma unroll
        for (int f = 0; f < 8; f++) eav[f] = 0.f;
    }
    __syncthreads();
    {
        int k0 = seg * 16;
        for (int kk = 0; kk < 16; kk++) {
            int k = k0 + kk;
            float acc = sbe1[k];
            #pragma unroll
            for (int f = 0; f < 8; f++) acc += eav[f] * sWe1[f * 64 + k];
            sTh[k * 128 + el4] = f2h((eg4 < NE) ? fmaxf(acc, 0.f) : 0.f);
        }
    }
    __syncthreads();

    short8 xa[4][2];
    #pragma unroll
    for (int rt = 0; rt < 4; rt++)
        #pragma unroll
        for (int s = 0; s < 2; s++)
            xa[rt][s] = *(const short8*)&sX[(rh * 64 + rt * 16 + ll) * 72 + s * 32 + quad * 8];

    f32x4 msg[4];
    #pragma unroll
    for (int rt = 0; rt < 4; rt++) msg[rt] = (f32x4){0.f, 0.f, 0.f, 0.f};

    const u16* gB0 = Bt2 + (0 * 4 + cq) * 512 + lane * 8;
    const u16* gB1 = Bt2 + (1 * 4 + cq) * 512 + lane * 8;
    const f32x4 zero = (f32x4){0.f, 0.f, 0.f, 0.f};
    const int tkoff = rh * 64 + quad * 4;

    #define LDR(dst, kcv, rtv) dst = *(const uint2*)&sTh[(kcv) * 128 + tkoff + (rtv) * 16];
    #define CVT(t, raw)                                                      \
        {                                                                    \
            __half2 _a = __builtin_bit_cast(__half2, (raw).x);               \
            __half2 _b = __builtin_bit_cast(__half2, (raw).y);               \
            float2 _fa = __half22float2(_a);                                 \
            float2 _fb = __half22float2(_b);                                 \
            t = (f32x4){_fa.x, _fa.y, _fb.x, _fb.y};                         \
        }

    short8 c00 = *(const short8*)(gB0);
    short8 c01 = *(const short8*)(gB1);
    short8 c10 = *(const short8*)(gB0 + 4096);
    short8 c11 = *(const short8*)(gB1 + 4096);
    uint2 tkA[4], tkB[4];
    #pragma unroll
    for (int rt = 0; rt < 4; rt++) LDR(tkA[rt], 0, rt);

    for (int kc = 0; kc < 62; kc += 2) {
        short8 n00 = *(const short8*)(gB0 + (kc + 2) * 4096);
        short8 n01 = *(const short8*)(gB1 + (kc + 2) * 4096);
        short8 n10 = *(const short8*)(gB0 + (kc + 3) * 4096);
        short8 n11 = *(const short8*)(gB1 + (kc + 3) * 4096);
        #pragma unroll
        for (int rt = 0; rt < 4; rt++) LDR(tkB[rt], kc + 1, rt);
        #pragma unroll
        for (int rt = 0; rt < 4; rt++) {
            f32x4 q0 = __builtin_amdgcn_mfma_f32_16x16x32_f16(s2h(xa[rt][0]), s2h(c00), zero, 0, 0, 0);
            f32x4 q1 = __builtin_amdgcn_mfma_f32_16x16x32_f16(s2h(xa[rt][1]), s2h(c01), zero, 0, 0, 0);
            f32x4 t; CVT(t, tkA[rt]);
            msg[rt] += t * q0;
            msg[rt] += t * q1;
        }
        #pragma unroll
        for (int rt = 0; rt < 4; rt++) LDR(tkA[rt], kc + 2, rt);
        #pragma unroll
        for (int rt = 0; rt < 4; rt++) {
            f32x4 q0 = __builtin_amdgcn_mfma_f32_16x16x32_f16(s2h(xa[rt][0]), s2h(c10), zero, 0, 0, 0);
            f32x4 q1 = __builtin_amdgcn_mfma_f32_16x16x32_f16(s2h(xa[rt][1]), s2h(c11), zero, 0, 0, 0);
            f32x4 t; CVT(t, tkB[rt]);
            msg[rt] += t * q0;
            msg[rt] += t * q1;
        }
        c00 = n00; c01 = n01; c10 = n10; c11 = n11;
    }
    {
        short8 n00 = *(const short8*)(gB0 + 64 * 4096);
        short8 n01 = *(const short8*)(gB1 + 64 * 4096);
        #pragma unroll
        for (int rt = 0; rt < 4; rt++) LDR(tkB[rt], 63, rt);
        #pragma unroll
        for (int rt = 0; rt < 4; rt++) {
            f32x4 q0 = __builtin_amdgcn_mfma_f32_16x16x32_f16(s2h(xa[rt][0]), s2h(c00), zero, 0, 0, 0);
            f32x4 q1 = __builtin_amdgcn_mfma_f32_16x16x32_f16(s2h(xa[rt][1]), s2h(c01), zero, 0, 0, 0);
            f32x4 t; CVT(t, tkA[rt]);
            msg[rt] += t * q0;
            msg[rt] += t * q1;
        }
        #pragma unroll
        for (int rt = 0; rt < 4; rt++) LDR(tkA[rt], 64, rt);
        #pragma unroll
        for (int rt = 0; rt < 4; rt++) {
            f32x4 q0 = __builtin_amdgcn_mfma_f32_16x16x32_f16(s2h(xa[rt][0]), s2h(c10), zero, 0, 0, 0);
            f32x4 q1 = __builtin_amdgcn_mfma_f32_16x16x32_f16(s2h(xa[rt][1]), s2h(c11), zero, 0, 0, 0);
            f32x4 t; CVT(t, tkB[rt]);
            msg[rt] += t * q0;
            msg[rt] += t * q1;
        }
        #pragma unroll
        for (int rt = 0; rt < 4; rt++) {
            f32x4 q0 = __builtin_amdgcn_mfma_f32_16x16x32_f16(s2h(xa[rt][0]), s2h(n00), zero, 0, 0, 0);
            f32x4 q1 = __builtin_amdgcn_mfma_f32_16x16x32_f16(s2h(xa[rt][1]), s2h(n01), zero, 0, 0, 0);
            f32x4 t; CVT(t, tkA[rt]);
            msg[rt] += t * q0;
            msg[rt] += t * q1;
        }
    }
    #undef LDR
    #undef CVT

    #pragma unroll
    for (int rt = 0; rt < 4; rt++) {
        #pragma unroll
        for (int r = 0; r < 4; r++) {
            int el = rh * 64 + rt * 16 + quad * 4 + r;
            int eg = e0 + el;
            if (eg < NE) {
                int d = sDst[el];
                atomicAdd(&agg[d * 64 + cq * 16 + ll], msg[rt][r]);
            }
        }
    }
}

__global__ __launch_bounds__(256) void k_gru(const u16* __restrict__ x1b,
                                             const float* __restrict__ agg,
                                             const u16* __restrict__ Wib,
                                             const u16* __restrict__ Whb,
                                             const u16* __restrict__ Wrb,
                                             const float* __restrict__ bconv,
                                             const float* __restrict__ bi,
                                             const float* __restrict__ bh,
                                             const int* __restrict__ batch,
                                             float* __restrict__ pooled) {
    __shared__ __align__(16) u16 sX2[64 * 72];
    __shared__ float hbuf[64 * 65];
    __shared__ int sBatch[64];
    const int tid = threadIdx.x;
    const int lane = tid & 63, wv = tid >> 6;
    const int ll = lane & 15, quad = lane >> 4;
    const int n0 = blockIdx.x * 64;

    if (tid < 64) {
        int n = n0 + tid;
        sBatch[tid] = (n < NN) ? batch[n] : -1;
    }
    short8 ha[2];
    {
        int n = n0 + wv * 16 + ll;
        #pragma unroll
        for (int kc = 0; kc < 2; kc++) {
            if (n < NN) ha[kc] = *(const short8*)(x1b + n * 64 + kc * 32 + quad * 8);
            else        ha[kc] = (short8){0,0,0,0,0,0,0,0};
        }
    }
    f32x4 acc1[4];
    #pragma unroll
    for (int c = 0; c < 4; c++) acc1[c] = (f32x4){0.f, 0.f, 0.f, 0.f};
    #pragma unroll
    for (int kc = 0; kc < 2; kc++) {
        #pragma unroll
        for (int c = 0; c < 4; c++) {
            short8 b = *(const short8*)&Wrb[(c * 2 + kc) * 512 + lane * 8];
            acc1[c] = __builtin_amdgcn_mfma_f32_16x16x32_f16(s2h(ha[kc]), s2h(b), acc1[c], 0, 0, 0);
        }
    }
    #pragma unroll
    for (int c = 0; c < 4; c++) {
        int col = c * 16 + ll;
        float bcv = bconv[col];
        #pragma unroll
        for (int r = 0; r < 4; r++) {
            int row = wv * 16 + quad * 4 + r;
            int n = n0 + row;
            float v = 0.f;
            if (n < NN) v = fmaxf(acc1[c][r] + agg[n * 64 + col] + bcv, 0.f);
            sX2[row * 72 + col] = f2h(v);
        }
    }
    __syncthreads();

    short8 xa[2];
    #pragma unroll
    for (int kc = 0; kc < 2; kc++)
        xa[kc] = *(const short8*)&sX2[(wv * 16 + ll) * 72 + kc * 32 + quad * 8];

    f32x4 agi[12], agh[12];
    #pragma unroll
    for (int c = 0; c < 12; c++) { agi[c] = (f32x4){0.f,0.f,0.f,0.f}; agh[c] = (f32x4){0.f,0.f,0.f,0.f}; }
    #pragma unroll
    for (int kc = 0; kc < 2; kc++) {
        #pragma unroll
        for (int c = 0; c < 12; c++) {
            short8 bi8 = *(const short8*)&Wib[(c * 2 + kc) * 512 + lane * 8];
            short8 bh8 = *(const short8*)&Whb[(c * 2 + kc) * 512 + lane * 8];
            agi[c] = __builtin_amdgcn_mfma_f32_16x16x32_f16(s2h(xa[kc]), s2h(bi8), agi[c], 0, 0, 0);
            agh[c] = __builtin_amdgcn_mfma_f32_16x16x32_f16(s2h(ha[kc]), s2h(bh8), agh[c], 0, 0, 0);
        }
    }

    float hnv[4][4];
    #pragma unroll
    for (int c0 = 0; c0 < 4; c0++) {
        int d = c0 * 16 + ll;
        float bir = bi[d],        bhr = bh[d];
        float biz = bi[64 + d],   bhz = bh[64 + d];
        float bin = bi[128 + d],  bhn = bh[128 + d];
        #pragma unroll
        for (int r = 0; r < 4; r++) {
            int row = wv * 16 + quad * 4 + r;
            int n = n0 + row;
            float gir = agi[c0][r] + bir,     ghr = agh[c0][r] + bhr;
            float giz = agi[c0 + 4][r] + biz, ghz = agh[c0 + 4][r] + bhz;
            float gin = agi[c0 + 8][r] + bin, ghn = agh[c0 + 8][r] + bhn;
            float rg = __fdividef(1.f, 1.f + __expf(-(gir + ghr)));
            float zg = __fdividef(1.f, 1.f + __expf(-(giz + ghz)));
            float xt = gin + rg * ghn;
            float e2 = __expf(2.f * xt);
            float ng = 1.f - __fdividef(2.f, e2 + 1.f);
            float hv = (n < NN) ? h2f(x1b[n * 64 + d]) : 0.f;
            hnv[c0][r] = (n < NN) ? ((1.f - zg) * ng + zg * hv) : 0.f;
        }
    }
    __syncthreads();

    #pragma unroll
    for (int c0 = 0; c0 < 4; c0++) {
        int d = c0 * 16 + ll;
        #pragma unroll
        for (int r = 0; r < 4; r++) {
            int row = wv * 16 + quad * 4 + r;
            hbuf[row * 65 + d] = hnv[c0][r];
        }
    }
    __syncthreads();

    {
        int d = lane;
        float sum = 0.f;
        int pb = sBatch[wv * 16];
        #pragma unroll
        for (int rr = 0; rr < 16; rr++) {
            int row = wv * 16 + rr;
            int b = sBatch[row];
            float v = hbuf[row * 65 + d];
            if (b != pb) {
                if (pb >= 0) atomicAdd(&pooled[pb * 64 + d], sum);
                sum = v; pb = b;
            } else {
                sum += v;
            }
        }
        if (pb >= 0) atomicAdd(&pooled[pb * 64 + d], sum);
    }
}

__global__ __launch_bounds__(256) void k_heads(const float* __restrict__ pooled,
                                               const u16* __restrict__ W11b, const float* __restrict__ b11,
                                               const u16* __restrict__ W12b, const float* __restrict__ b12,
                                               const float* __restrict__ W13, const float* __restrict__ b13,
                                               const u16* __restrict__ W21b, const float* __restrict__ b21,
                                               const u16* __restrict__ W22b, const float* __restrict__ b22,
                                               const float* __restrict__ W23, const float* __restrict__ b23,
                                               float* __restrict__ out) {
    __shared__ __align__(16) u16 sY[64 * 72];
    const int tid = threadIdx.x;
    const int lane = tid & 63, wv = tid >> 6;
    const int ll = lane & 15, quad = lane >> 4;
    const int g0 = blockIdx.x * 64;
    const f32x4 zero = (f32x4){0.f, 0.f, 0.f, 0.f};

    short8 pa[2];
    {
        int g = g0 + wv * 16 + ll;
        #pragma unroll
        for (int kc = 0; kc < 2; kc++) {
            if (g < NG) {
                const float* pr = pooled + g * 64 + kc * 32 + quad * 8;
                f32x4 v0 = *(const f32x4*)(pr);
                f32x4 v1 = *(const f32x4*)(pr + 4);
                short8 s;
                #pragma unroll
                for (int j = 0; j < 4; j++) {
                    s[j]     = (short)f2h(v0[j]);
                    s[4 + j] = (short)f2h(v1[j]);
                }
                pa[kc] = s;
            } else {
                pa[kc] = (short8){0,0,0,0,0,0,0,0};
            }
        }
    }
    const u16* W1s[2] = {W11b, W21b}; const float* b1s[2] = {b11, b21};
    const u16* W2s[2] = {W12b, W22b}; const float* b2s[2] = {b12, b22};
    const float* W3s[2] = {W13, W23}; const float* b3s[2] = {b13, b23};
    #pragma unroll
    for (int hd = 0; hd < 2; hd++) {
        f32x4 a1[4];
        #pragma unroll
        for (int c = 0; c < 4; c++) a1[c] = zero;
        #pragma unroll
        for (int kc = 0; kc < 2; kc++)
            #pragma unroll
            for (int c = 0; c < 4; c++) {
                short8 b = *(const short8*)&W1s[hd][(c * 2 + kc) * 512 + lane * 8];
                a1[c] = __builtin_amdgcn_mfma_f32_16x16x32_f16(s2h(pa[kc]), s2h(b), a1[c], 0, 0, 0);
            }
        #pragma unroll
        for (int c = 0; c < 4; c++) {
            int col = c * 16 + ll;
            float bv = b1s[hd][col];
            #pragma unroll
            for (int r = 0; r < 4; r++) {
                int row = wv * 16 + quad * 4 + r;
                sY[row * 72 + col] = f2h(fmaxf(a1[c][r] + bv, 0.f));
            }
        }
        __syncthreads();
        short8 ya[2];
        #pragma unroll
        for (int kc = 0; kc < 2; kc++)
            ya[kc] = *(const short8*)&sY[(wv * 16 + ll) * 72 + kc * 32 + quad * 8];
        f32x4 a2[4];
        #pragma unroll
        for (int c = 0; c < 4; c++) a2[c] = zero;
        #pragma unroll
        for (int kc = 0; kc < 2; kc++)
            #pragma unroll
            for (int c = 0; c < 4; c++) {
                short8 b = *(const short8*)&W2s[hd][(c * 2 + kc) * 512 + lane * 8];
                a2[c] = __builtin_amdgcn_mfma_f32_16x16x32_f16(s2h(ya[kc]), s2h(b), a2[c], 0, 0, 0);
            }
        #pragma unroll
        for (int r = 0; r < 4; r++) {
            float part = 0.f;
            #pragma unroll
            for (int c = 0; c < 4; c++) {
                int col = c * 16 + ll;
                part += fmaxf(a2[c][r] + b2s[hd][col], 0.f) * W3s[hd][col];
            }
            part += __shfl_xor(part, 1, 64);
            part += __shfl_xor(part, 2, 64);
            part += __shfl_xor(part, 4, 64);
            part += __shfl_xor(part, 8, 64);
            if (ll == 0) {
                int g = g0 + wv * 16 + quad * 4 + r;
                if (g < NG) out[g * 2 + hd] = part + b3s[hd][0];
            }
        }
        __syncthreads();
    }
}

extern "C" void kernel_launch(void* const* d_in, const int* in_sizes, int n_in,
                              void* d_out, int out_size, void* d_ws, size_t ws_size,
                              hipStream_t stream) {
    const float* x     = (const float*)d_in[0];
    const int* eidx    = (const int*)d_in[1];
    const float* ea    = (const float*)d_in[2];
    const int* batch   = (const int*)d_in[3];
    const float* W0    = (const float*)d_in[4];  const float* b0    = (const float*)d_in[5];
    const float* We1   = (const float*)d_in[6];  const float* be1   = (const float*)d_in[7];
    const float* We2   = (const float*)d_in[8];  const float* be2   = (const float*)d_in[9];
    const float* Wroot = (const float*)d_in[10]; const float* bconv = (const float*)d_in[11];
    const float* Wi    = (const float*)d_in[12]; const float* Wh    = (const float*)d_in[13];
    const float* bi    = (const float*)d_in[14]; const float* bh    = (const float*)d_in[15];
    const float* W11   = (const float*)d_in[16]; const float* b11   = (const float*)d_in[17];
    const float* W12   = (const float*)d_in[18]; const float* b12   = (const float*)d_in[19];
    const float* W13   = (const float*)d_in[20]; const float* b13   = (const float*)d_in[21];
    const float* W21   = (const float*)d_in[22]; const float* b21   = (const float*)d_in[23];
    const float* W22   = (const float*)d_in[24]; const float* b22   = (const float*)d_in[25];
    const float* W23   = (const float*)d_in[26]; const float* b23   = (const float*)d_in[27];
    float* out = (float*)d_out;

    // workspace: total 10,478,592 B
    char* ws = (char*)d_ws;
    float* agg    = (float*)(ws);                       // 6,400,000 B
    u16*   x1b    = (u16*)(ws + 6400000);               // 3,200,000 B
    u16*   Bt2    = (u16*)(ws + 9600000);               //   532,480 B
    float* pooled = (float*)(ws + 10132480);            //   256,000 B
    u16*   Wib    = (u16*)(ws + 10388480);              //    24,576 B
    u16*   Whb    = (u16*)(ws + 10413056);              //    24,576 B
    u16*   Wrb    = (u16*)(ws + 10437632);              //     8,192 B
    u16*   W11b   = (u16*)(ws + 10445824);              //     8,192 B
    u16*   W12b   = (u16*)(ws + 10454016);              //     8,192 B
    u16*   W21b   = (u16*)(ws + 10462208);              //     8,192 B
    u16*   W22b   = (u16*)(ws + 10470400);              //     8,192 B

    const size_t SMEM = 38400;
    int maxB = 0;
    int G = 391;
    if (hipOccupancyMaxActiveBlocksPerMultiprocessor(&maxB, k_mega, 512, SMEM) == hipSuccess
        && maxB >= 1) {
        long cap = (long)maxB * 256;
        if (cap < G) G = (int)cap;
    }
    if (G < 1) G = 1;
    void* kargs[] = {
        (void*)&x, (void*)&eidx, (void*)&ea, (void*)&batch,
        (void*)&W0, (void*)&b0, (void*)&We1, (void*)&be1, (void*)&We2, (void*)&be2,
        (void*)&Wroot, (void*)&bconv, (void*)&Wi, (void*)&Wh, (void*)&bi, (void*)&bh,
        (void*)&W13, (void*)&b13, (void*)&W23, (void*)&b23,
        (void*)&b11, (void*)&b12, (void*)&b21, (void*)&b22,
        (void*)&W11, (void*)&W12, (void*)&W21, (void*)&W22,
        (void*)&out,
        (void*)&agg, (void*)&x1b, (void*)&Bt2, (void*)&pooled,
        (void*)&Wib, (void*)&Whb, (void*)&Wrb,
        (void*)&W11b, (void*)&W12b, (void*)&W21b, (void*)&W22b
    };
    hipError_t err = hipLaunchCooperativeKernel((void*)k_mega, dim3(G), dim3(512),
                                                kargs, SMEM, stream);
    if (err != hipSuccess) {
        (void)hipGetLastError();   // clear sticky error, fall back to classic path
        hipLaunchKernelGGL(k_pre, dim3(1884), dim3(256), 0, stream,
                           x, W0, b0, x1b, We2, be2, agg, pooled, Bt2,
                           Wi, Wh, Wroot, Wib, Whb, Wrb,
                           W11, W12, W21, W22, W11b, W12b, W21b, W22b);
        hipLaunchKernelGGL(k_msg, dim3(782), dim3(512), 0, stream,
                           ea, eidx, We1, be1, x1b, Bt2, agg);
        hipLaunchKernelGGL(k_gru, dim3(391), dim3(256), 0, stream, x1b, agg,
                           Wib, Whb, Wrb, bconv, bi, bh, batch, pooled);
        hipLaunchKernelGGL(k_heads, dim3(16), dim3(256), 0, stream, pooled,
                           W11b, b11, W12b, b12, W13, b13, W21b, b21, W22b, b22, W23, b23, out);
    }
}

// Round 14
// 222.650 us; speedup vs baseline: 2.3421x; 2.3421x over previous
//
#include <hip/hip_runtime.h>
#include <hip/hip_bf16.h>
#include <hip/hip_fp16.h>

#define NN 25000
#define NE 100000
#define FIN 32
#define DD 64
#define NG 1000

typedef unsigned short u16;
typedef __attribute__((ext_vector_type(8))) short short8;
typedef __attribute__((ext_vector_type(8))) _Float16 f16x8;
typedef __attribute__((ext_vector_type(4))) float f32x4;

__device__ __forceinline__ u16 f2h(float f) {
    __half h = __float2half(f);
    return __builtin_bit_cast(u16, h);
}
__device__ __forceinline__ float h2f(u16 u) {
    __half h = __builtin_bit_cast(__half, u);
    return __half2float(h);
}
__device__ __forceinline__ f16x8 s2h(short8 v) { return __builtin_bit_cast(f16x8, v); }
// edge_index may be int64 read as int32 words: odd words would all be 0.
__device__ __forceinline__ bool idx_is_i64(const int* e) {
    return (e[1] == 0) & (e[3] == 0) & (e[5] == 0) & (e[7] == 0) & (e[9] == 0);
}
__device__ __forceinline__ int ld_src(const int* e, int i, bool i64) {
    return i64 ? e[2 * i] : e[i];
}
__device__ __forceinline__ int ld_dst(const int* e, int i, bool i64) {
    return i64 ? e[2 * (NE + i)] : e[NE + i];
}

// ---- fused pre-pass (round-9 structure + head-weight prebuild) ---------------------------
// blocks [0,1563): lin0 (16 rows/block) -> x1b f16
// blocks [1563,1628): Bt2 chunk kc = bid-1563
// blocks [1628,1884): zero agg/pooled + fragment-major f16 Wib/Whb/Wrb + head weights
__global__ __launch_bounds__(256) void k_pre(const float* __restrict__ x,
                                             const float* __restrict__ W0,
                                             const float* __restrict__ b0,
                                             u16* __restrict__ x1b,
                                             const float* __restrict__ We2,
                                             const float* __restrict__ be2,
                                             float* __restrict__ agg,
                                             float* __restrict__ pooled,
                                             u16* __restrict__ Bt2,
                                             const float* __restrict__ Wi,
                                             const float* __restrict__ Wh,
                                             const float* __restrict__ Wroot,
                                             u16* __restrict__ Wib,
                                             u16* __restrict__ Whb,
                                             u16* __restrict__ Wrb,
                                             const float* __restrict__ W11,
                                             const float* __restrict__ W12,
                                             const float* __restrict__ W21,
                                             const float* __restrict__ W22,
                                             u16* __restrict__ W11b,
                                             u16* __restrict__ W12b,
                                             u16* __restrict__ W21b,
                                             u16* __restrict__ W22b) {
    __shared__ float sbuf[4096 + 512];
    int tid = threadIdx.x;
    if (blockIdx.x < 1563) {
        float* sW = sbuf;            // [FIN*DD] = 2048
        float* sx = sbuf + 4096;     // [16*FIN] = 512
        for (int i = tid; i < FIN * DD; i += 256) sW[i] = W0[i];
        int nbase = blockIdx.x * 16;
        for (int i = tid; i < 16 * FIN; i += 256) {
            int nl = i >> 5, f = i & 31;
            int n = nbase + nl;
            sx[i] = (n < NN) ? x[n * FIN + f] : 0.f;
        }
        __syncthreads();
        int lane = tid & 63, nl = tid >> 6;
        float bias = b0[lane];
        #pragma unroll
        for (int rr = 0; rr < 4; rr++) {
            int row = nl * 4 + rr;
            int n = nbase + row;
            if (n < NN) {
                float acc = bias;
                #pragma unroll
                for (int f = 0; f < FIN; f++) acc += sx[row * FIN + f] * sW[f * DD + lane];
                x1b[n * DD + lane] = f2h(fmaxf(acc, 0.f));
            }
        }
    } else if (blockIdx.x < 1628) {
        int kc = blockIdx.x - 1563;                 // [0,65)
        const float* src = (kc < 64) ? (We2 + kc * 4096) : be2;
        for (int i = tid; i < 4096; i += 256) sbuf[i] = src[i];
        __syncthreads();
        for (int m = tid; m < 4096; m += 256) {
            int f = m >> 9, ln = (m >> 3) & 63, j = m & 7;
            int s = f >> 2, c = f & 3;
            int o = c * 16 + (ln & 15);
            int rlow = s * 32 + (ln >> 4) * 8 + j;
            Bt2[kc * 4096 + m] = f2h(sbuf[rlow * 64 + o]);
        }
    } else {
        int tid0 = (blockIdx.x - 1628) * 256 + threadIdx.x;
        const int STR = 256 * 256;
        for (int i = tid0; i < NN * DD; i += STR) agg[i] = 0.f;
        for (int i = tid0; i < NG * DD; i += STR) pooled[i] = 0.f;
        for (int i = tid0; i < 12288; i += STR) {
            int fr = i >> 9, lane = (i >> 3) & 63, j = i & 7;
            int c = fr >> 1, kcx = fr & 1;
            int row = c * 16 + (lane & 15);
            int col = kcx * 32 + (lane >> 4) * 8 + j;
            Wib[i] = f2h(Wi[row * 64 + col]);
            Whb[i] = f2h(Wh[row * 64 + col]);
        }
        // Wrb + 4 head matrices: contraction-over-first-index layout (Wrb pattern)
        for (int i = tid0; i < 4096; i += STR) {
            int fr = i >> 9, lane = (i >> 3) & 63, j = i & 7;
            int c = fr >> 1, kcx = fr & 1;
            int row = c * 16 + (lane & 15);
            int col = kcx * 32 + (lane >> 4) * 8 + j;
            int idx = col * 64 + row;
            Wrb[i]  = f2h(Wroot[idx]);
            W11b[i] = f2h(W11[idx]);
            W12b[i] = f2h(W12[idx]);
            W21b[i] = f2h(W21[idx]);
            W22b[i] = f2h(W22[idx]);
        }
    }
}

// ---- fused NNConv message GEMM + scatter (round-9 verbatim: best measured) ---------------
__global__ __launch_bounds__(512, 4) void k_msg(const float* __restrict__ ea,
                                                const int* __restrict__ eidx,
                                                const float* __restrict__ We1,
                                                const float* __restrict__ be1,
                                                const u16* __restrict__ x1b,
                                                const u16* __restrict__ Bt2,
                                                float* __restrict__ agg) {
    __shared__ __align__(16) u16 sX[128 * 72];       // gathered x1 rows (f16), pad 72
    __shared__ __align__(16) u16 sTh[65 * 128 + 64]; // t transposed [k][e], f16; row 64 = 1.0
    __shared__ float sWe1[8 * 64];
    __shared__ float sbe1[64];
    __shared__ int sDst[128];
    const int tid = threadIdx.x;
    const int lane = tid & 63, wv = tid >> 6;
    const int ll = lane & 15, quad = lane >> 4;
    const int rh = wv >> 2, cq = wv & 3;       // row-half, col-quarter
    const int e0 = blockIdx.x * 128;
    const bool i64 = idx_is_i64(eidx);

    if (tid < 512) sWe1[tid] = We1[tid];
    if (tid < 64) sbe1[tid] = be1[tid];
    if (tid < 128) {
        sDst[tid] = (e0 + tid < NE) ? ld_dst(eidx, e0 + tid, i64) : 0;
        sTh[64 * 128 + tid] = 0x3C00;          // bias chunk: t = 1.0 (f16)
    }

    // phase 1: gather x1 rows (f16) for 128 edges; each thread: 32 B of one row
    const int el4 = tid >> 2, seg = tid & 3;
    const int eg4 = e0 + el4;
    {
        if (eg4 < NE) {
            int sv = ld_src(eidx, eg4, i64);
            const u16* xr = x1b + sv * 64 + seg * 16;
            *(uint4*)&sX[el4 * 72 + seg * 16]     = *(const uint4*)(xr);
            *(uint4*)&sX[el4 * 72 + seg * 16 + 8] = *(const uint4*)(xr + 8);
        } else {
            uint4 z = make_uint4(0, 0, 0, 0);
            *(uint4*)&sX[el4 * 72 + seg * 16]     = z;
            *(uint4*)&sX[el4 * 72 + seg * 16 + 8] = z;
        }
    }
    float eav[8];
    if (eg4 < NE) {
        f32x4 v0 = *(const f32x4*)(ea + eg4 * 8);
        f32x4 v1 = *(const f32x4*)(ea + eg4 * 8 + 4);
        #pragma unroll
        for (int f = 0; f < 4; f++) { eav[f] = v0[f]; eav[4 + f] = v1[f]; }
    } else {
        #pragma unroll
        for (int f = 0; f < 8; f++) eav[f] = 0.f;
    }
    __syncthreads();

    // phase 2: t[e,k] = relu(ea @ We1 + be1); each thread: 16 k-values of its edge (f16)
    {
        int k0 = seg * 16;
        for (int kk = 0; kk < 16; kk++) {
            int k = k0 + kk;
            float acc = sbe1[k];
            #pragma unroll
            for (int f = 0; f < 8; f++) acc += eav[f] * sWe1[f * 64 + k];
            sTh[k * 128 + el4] = f2h((eg4 < NE) ? fmaxf(acc, 0.f) : 0.f);
        }
    }
    __syncthreads();   // last barrier — K-loop below is barrier-free

    // fixed A-fragments: this wave's 4 row-tiles (rows rh*64 .. rh*64+63)
    short8 xa[4][2];
    #pragma unroll
    for (int rt = 0; rt < 4; rt++)
        #pragma unroll
        for (int s = 0; s < 2; s++)
            xa[rt][s] = *(const short8*)&sX[(rh * 64 + rt * 16 + ll) * 72 + s * 32 + quad * 8];

    f32x4 msg[4];
    #pragma unroll
    for (int rt = 0; rt < 4; rt++) msg[rt] = (f32x4){0.f, 0.f, 0.f, 0.f};

    // coalesced per-lane B pointers for this wave's column quarter
    const u16* gB0 = Bt2 + (0 * 4 + cq) * 512 + lane * 8;
    const u16* gB1 = Bt2 + (1 * 4 + cq) * 512 + lane * 8;
    const f32x4 zero = (f32x4){0.f, 0.f, 0.f, 0.f};
    const int tkoff = rh * 64 + quad * 4;

    // raw tk prefetch: ds_read_b64 (4 f16); convert at use
    #define LDR(dst, kcv, rtv) dst = *(const uint2*)&sTh[(kcv) * 128 + tkoff + (rtv) * 16];
    #define CVT(t, raw)                                                      \
        {                                                                    \
            __half2 _a = __builtin_bit_cast(__half2, (raw).x);               \
            __half2 _b = __builtin_bit_cast(__half2, (raw).y);               \
            float2 _fa = __half22float2(_a);                                 \
            float2 _fb = __half22float2(_b);                                 \
            t = (f32x4){_fa.x, _fa.y, _fb.x, _fb.y};                         \
        }

    // pipeline prologue: B for kc 0,1 in flight; raw tk for kc 0 in regs
    short8 c00 = *(const short8*)(gB0);
    short8 c01 = *(const short8*)(gB1);
    short8 c10 = *(const short8*)(gB0 + 4096);
    short8 c11 = *(const short8*)(gB1 + 4096);
    uint2 tkA[4], tkB[4];
    #pragma unroll
    for (int rt = 0; rt < 4; rt++) LDR(tkA[rt], 0, rt);

    for (int kc = 0; kc < 62; kc += 2) {
        // prefetch B two kc ahead
        short8 n00 = *(const short8*)(gB0 + (kc + 2) * 4096);
        short8 n01 = *(const short8*)(gB1 + (kc + 2) * 4096);
        short8 n10 = *(const short8*)(gB0 + (kc + 3) * 4096);
        short8 n11 = *(const short8*)(gB1 + (kc + 3) * 4096);
        // prefetch raw tk one kc ahead
        #pragma unroll
        for (int rt = 0; rt < 4; rt++) LDR(tkB[rt], kc + 1, rt);
        // compute kc (independent q0,q1; tk converted just-in-time)
        #pragma unroll
        for (int rt = 0; rt < 4; rt++) {
            f32x4 q0 = __builtin_amdgcn_mfma_f32_16x16x32_f16(s2h(xa[rt][0]), s2h(c00), zero, 0, 0, 0);
            f32x4 q1 = __builtin_amdgcn_mfma_f32_16x16x32_f16(s2h(xa[rt][1]), s2h(c01), zero, 0, 0, 0);
            f32x4 t; CVT(t, tkA[rt]);
            msg[rt] += t * q0;
            msg[rt] += t * q1;
        }
        #pragma unroll
        for (int rt = 0; rt < 4; rt++) LDR(tkA[rt], kc + 2, rt);
        // compute kc+1
        #pragma unroll
        for (int rt = 0; rt < 4; rt++) {
            f32x4 q0 = __builtin_amdgcn_mfma_f32_16x16x32_f16(s2h(xa[rt][0]), s2h(c10), zero, 0, 0, 0);
            f32x4 q1 = __builtin_amdgcn_mfma_f32_16x16x32_f16(s2h(xa[rt][1]), s2h(c11), zero, 0, 0, 0);
            f32x4 t; CVT(t, tkB[rt]);
            msg[rt] += t * q0;
            msg[rt] += t * q1;
        }
        c00 = n00; c01 = n01; c10 = n10; c11 = n11;
    }
    // tail: kc = 62, 63 (in c*), then bias chunk 64 (prefetched into n0*)
    {
        short8 n00 = *(const short8*)(gB0 + 64 * 4096);
        short8 n01 = *(const short8*)(gB1 + 64 * 4096);
        #pragma unroll
        for (int rt = 0; rt < 4; rt++) LDR(tkB[rt], 63, rt);
        #pragma unroll
        for (int rt = 0; rt < 4; rt++) {
            f32x4 q0 = __builtin_amdgcn_mfma_f32_16x16x32_f16(s2h(xa[rt][0]), s2h(c00), zero, 0, 0, 0);
            f32x4 q1 = __builtin_amdgcn_mfma_f32_16x16x32_f16(s2h(xa[rt][1]), s2h(c01), zero, 0, 0, 0);
            f32x4 t; CVT(t, tkA[rt]);
            msg[rt] += t * q0;
            msg[rt] += t * q1;
        }
        #pragma unroll
        for (int rt = 0; rt < 4; rt++) LDR(tkA[rt], 64, rt);  // = 1.0
        #pragma unroll
        for (int rt = 0; rt < 4; rt++) {
            f32x4 q0 = __builtin_amdgcn_mfma_f32_16x16x32_f16(s2h(xa[rt][0]), s2h(c10), zero, 0, 0, 0);
            f32x4 q1 = __builtin_amdgcn_mfma_f32_16x16x32_f16(s2h(xa[rt][1]), s2h(c11), zero, 0, 0, 0);
            f32x4 t; CVT(t, tkB[rt]);
            msg[rt] += t * q0;
            msg[rt] += t * q1;
        }
        #pragma unroll
        for (int rt = 0; rt < 4; rt++) {
            f32x4 q0 = __builtin_amdgcn_mfma_f32_16x16x32_f16(s2h(xa[rt][0]), s2h(n00), zero, 0, 0, 0);
            f32x4 q1 = __builtin_amdgcn_mfma_f32_16x16x32_f16(s2h(xa[rt][1]), s2h(n01), zero, 0, 0, 0);
            f32x4 t; CVT(t, tkA[rt]);
            msg[rt] += t * q0;
            msg[rt] += t * q1;
        }
    }
    #undef LDR
    #undef CVT

    // epilogue: row = rh*64 + rt*16 + quad*4 + r, col = cq*16 + ll; scatter into agg[dst]
    #pragma unroll
    for (int rt = 0; rt < 4; rt++) {
        #pragma unroll
        for (int r = 0; r < 4; r++) {
            int el = rh * 64 + rt * 16 + quad * 4 + r;
            int eg = e0 + el;
            if (eg < NE) {
                int d = sDst[el];
                atomicAdd(&agg[d * 64 + cq * 16 + ll], msg[rt][r]);
            }
        }
    }
}

// ---- GRU via MFMA (round-9 f16 path; fast tanh/sigmoid) ----------------------------------
__global__ __launch_bounds__(256) void k_gru(const u16* __restrict__ x1b,
                                             const float* __restrict__ agg,
                                             const u16* __restrict__ Wib,
                                             const u16* __restrict__ Whb,
                                             const u16* __restrict__ Wrb,
                                             const float* __restrict__ bconv,
                                             const float* __restrict__ bi,
                                             const float* __restrict__ bh,
                                             const int* __restrict__ batch,
                                             float* __restrict__ pooled) {
    __shared__ __align__(16) u16 sX2[64 * 72];
    __shared__ float hbuf[64 * 65];
    __shared__ int sBatch[64];
    const int tid = threadIdx.x;
    const int lane = tid & 63, wv = tid >> 6;
    const int ll = lane & 15, quad = lane >> 4;
    const int n0 = blockIdx.x * 64;

    if (tid < 64) {
        int n = n0 + tid;
        sBatch[tid] = (n < NN) ? batch[n] : -1;
    }

    short8 ha[2];
    {
        int n = n0 + wv * 16 + ll;
        #pragma unroll
        for (int kc = 0; kc < 2; kc++) {
            if (n < NN) ha[kc] = *(const short8*)(x1b + n * 64 + kc * 32 + quad * 8);
            else        ha[kc] = (short8){0,0,0,0,0,0,0,0};
        }
    }
    f32x4 acc1[4];
    #pragma unroll
    for (int c = 0; c < 4; c++) acc1[c] = (f32x4){0.f, 0.f, 0.f, 0.f};
    #pragma unroll
    for (int kc = 0; kc < 2; kc++) {
        #pragma unroll
        for (int c = 0; c < 4; c++) {
            short8 b = *(const short8*)&Wrb[(c * 2 + kc) * 512 + lane * 8];
            acc1[c] = __builtin_amdgcn_mfma_f32_16x16x32_f16(s2h(ha[kc]), s2h(b), acc1[c], 0, 0, 0);
        }
    }
    #pragma unroll
    for (int c = 0; c < 4; c++) {
        int col = c * 16 + ll;
        float bcv = bconv[col];
        #pragma unroll
        for (int r = 0; r < 4; r++) {
            int row = wv * 16 + quad * 4 + r;
            int n = n0 + row;
            float v = 0.f;
            if (n < NN) v = fmaxf(acc1[c][r] + agg[n * 64 + col] + bcv, 0.f);
            sX2[row * 72 + col] = f2h(v);
        }
    }
    __syncthreads();

    short8 xa[2];
    #pragma unroll
    for (int kc = 0; kc < 2; kc++)
        xa[kc] = *(const short8*)&sX2[(wv * 16 + ll) * 72 + kc * 32 + quad * 8];

    f32x4 agi[12], agh[12];
    #pragma unroll
    for (int c = 0; c < 12; c++) { agi[c] = (f32x4){0.f,0.f,0.f,0.f}; agh[c] = (f32x4){0.f,0.f,0.f,0.f}; }
    #pragma unroll
    for (int kc = 0; kc < 2; kc++) {
        #pragma unroll
        for (int c = 0; c < 12; c++) {
            short8 bi8 = *(const short8*)&Wib[(c * 2 + kc) * 512 + lane * 8];
            short8 bh8 = *(const short8*)&Whb[(c * 2 + kc) * 512 + lane * 8];
            agi[c] = __builtin_amdgcn_mfma_f32_16x16x32_f16(s2h(xa[kc]), s2h(bi8), agi[c], 0, 0, 0);
            agh[c] = __builtin_amdgcn_mfma_f32_16x16x32_f16(s2h(ha[kc]), s2h(bh8), agh[c], 0, 0, 0);
        }
    }

    float hnv[4][4];
    #pragma unroll
    for (int c0 = 0; c0 < 4; c0++) {
        int d = c0 * 16 + ll;
        float bir = bi[d],        bhr = bh[d];
        float biz = bi[64 + d],   bhz = bh[64 + d];
        float bin = bi[128 + d],  bhn = bh[128 + d];
        #pragma unroll
        for (int r = 0; r < 4; r++) {
            int row = wv * 16 + quad * 4 + r;
            int n = n0 + row;
            float gir = agi[c0][r] + bir,     ghr = agh[c0][r] + bhr;
            float giz = agi[c0 + 4][r] + biz, ghz = agh[c0 + 4][r] + bhz;
            float gin = agi[c0 + 8][r] + bin, ghn = agh[c0 + 8][r] + bhn;
            float rg = __fdividef(1.f, 1.f + __expf(-(gir + ghr)));
            float zg = __fdividef(1.f, 1.f + __expf(-(giz + ghz)));
            float xt = gin + rg * ghn;
            float e2 = __expf(2.f * xt);
            float ng = 1.f - __fdividef(2.f, e2 + 1.f);   // tanh(xt)
            float hv = (n < NN) ? h2f(x1b[n * 64 + d]) : 0.f;
            hnv[c0][r] = (n < NN) ? ((1.f - zg) * ng + zg * hv) : 0.f;
        }
    }
    __syncthreads();

    #pragma unroll
    for (int c0 = 0; c0 < 4; c0++) {
        int d = c0 * 16 + ll;
        #pragma unroll
        for (int r = 0; r < 4; r++) {
            int row = wv * 16 + quad * 4 + r;
            hbuf[row * 65 + d] = hnv[c0][r];
        }
    }
    __syncthreads();

    {
        int d = lane;
        float sum = 0.f;
        int pb = sBatch[wv * 16];
        #pragma unroll
        for (int rr = 0; rr < 16; rr++) {
            int row = wv * 16 + rr;
            int b = sBatch[row];
            float v = hbuf[row * 65 + d];
            if (b != pb) {
                if (pb >= 0) atomicAdd(&pooled[pb * 64 + d], sum);
                sum = v; pb = b;
            } else {
                sum += v;
            }
        }
        if (pb >= 0) atomicAdd(&pooled[pb * 64 + d], sum);
    }
}

// ---- heads via MFMA: 16 blocks x 64 graphs; weights pre-converted fragment-major ---------
__global__ __launch_bounds__(256) void k_heads(const float* __restrict__ pooled,
                                               const u16* __restrict__ W11b, const float* __restrict__ b11,
                                               const u16* __restrict__ W12b, const float* __restrict__ b12,
                                               const float* __restrict__ W13, const float* __restrict__ b13,
                                               const u16* __restrict__ W21b, const float* __restrict__ b21,
                                               const u16* __restrict__ W22b, const float* __restrict__ b22,
                                               const float* __restrict__ W23, const float* __restrict__ b23,
                                               float* __restrict__ out) {
    __shared__ __align__(16) u16 sY[64 * 72];
    const int tid = threadIdx.x;
    const int lane = tid & 63, wv = tid >> 6;
    const int ll = lane & 15, quad = lane >> 4;
    const int g0 = blockIdx.x * 64;
    const f32x4 zero = (f32x4){0.f, 0.f, 0.f, 0.f};

    // load pooled rows as f16 A-frags (row = wv*16 + ll, k = kc*32 + quad*8 + j)
    short8 pa[2];
    {
        int g = g0 + wv * 16 + ll;
        #pragma unroll
        for (int kc = 0; kc < 2; kc++) {
            if (g < NG) {
                const float* pr = pooled + g * 64 + kc * 32 + quad * 8;
                f32x4 v0 = *(const f32x4*)(pr);
                f32x4 v1 = *(const f32x4*)(pr + 4);
                short8 s;
                #pragma unroll
                for (int j = 0; j < 4; j++) {
                    s[j]     = (short)f2h(v0[j]);
                    s[4 + j] = (short)f2h(v1[j]);
                }
                pa[kc] = s;
            } else {
                pa[kc] = (short8){0,0,0,0,0,0,0,0};
            }
        }
    }

    const u16* W1s[2] = {W11b, W21b}; const float* b1s[2] = {b11, b21};
    const u16* W2s[2] = {W12b, W22b}; const float* b2s[2] = {b12, b22};
    const float* W3s[2] = {W13, W23}; const float* b3s[2] = {b13, b23};

    #pragma unroll
    for (int hd = 0; hd < 2; hd++) {
        // L1: y1 = relu(P @ W1 + b1)
        f32x4 a1[4];
        #pragma unroll
        for (int c = 0; c < 4; c++) a1[c] = zero;
        #pragma unroll
        for (int kc = 0; kc < 2; kc++)
            #pragma unroll
            for (int c = 0; c < 4; c++) {
                short8 b = *(const short8*)&W1s[hd][(c * 2 + kc) * 512 + lane * 8];
                a1[c] = __builtin_amdgcn_mfma_f32_16x16x32_f16(s2h(pa[kc]), s2h(b), a1[c], 0, 0, 0);
            }
        #pragma unroll
        for (int c = 0; c < 4; c++) {
            int col = c * 16 + ll;
            float bv = b1s[hd][col];
            #pragma unroll
            for (int r = 0; r < 4; r++) {
                int row = wv * 16 + quad * 4 + r;
                sY[row * 72 + col] = f2h(fmaxf(a1[c][r] + bv, 0.f));
            }
        }
        __syncthreads();
        // L2: y2 = relu(y1 @ W2 + b2); L3: dot with W3
        short8 ya[2];
        #pragma unroll
        for (int kc = 0; kc < 2; kc++)
            ya[kc] = *(const short8*)&sY[(wv * 16 + ll) * 72 + kc * 32 + quad * 8];
        f32x4 a2[4];
        #pragma unroll
        for (int c = 0; c < 4; c++) a2[c] = zero;
        #pragma unroll
        for (int kc = 0; kc < 2; kc++)
            #pragma unroll
            for (int c = 0; c < 4; c++) {
                short8 b = *(const short8*)&W2s[hd][(c * 2 + kc) * 512 + lane * 8];
                a2[c] = __builtin_amdgcn_mfma_f32_16x16x32_f16(s2h(ya[kc]), s2h(b), a2[c], 0, 0, 0);
            }
        #pragma unroll
        for (int r = 0; r < 4; r++) {
            float part = 0.f;
            #pragma unroll
            for (int c = 0; c < 4; c++) {
                int col = c * 16 + ll;
                part += fmaxf(a2[c][r] + b2s[hd][col], 0.f) * W3s[hd][col];
            }
            part += __shfl_xor(part, 1, 64);
            part += __shfl_xor(part, 2, 64);
            part += __shfl_xor(part, 4, 64);
            part += __shfl_xor(part, 8, 64);
            if (ll == 0) {
                int g = g0 + wv * 16 + quad * 4 + r;
                if (g < NG) out[g * 2 + hd] = part + b3s[hd][0];
            }
        }
        __syncthreads();   // sY reuse guard
    }
}

extern "C" void kernel_launch(void* const* d_in, const int* in_sizes, int n_in,
                              void* d_out, int out_size, void* d_ws, size_t ws_size,
                              hipStream_t stream) {
    const float* x     = (const float*)d_in[0];
    const int* eidx    = (const int*)d_in[1];
    const float* ea    = (const float*)d_in[2];
    const int* batch   = (const int*)d_in[3];
    const float* W0    = (const float*)d_in[4];  const float* b0    = (const float*)d_in[5];
    const float* We1   = (const float*)d_in[6];  const float* be1   = (const float*)d_in[7];
    const float* We2   = (const float*)d_in[8];  const float* be2   = (const float*)d_in[9];
    const float* Wroot = (const float*)d_in[10]; const float* bconv = (const float*)d_in[11];
    const float* Wi    = (const float*)d_in[12]; const float* Wh    = (const float*)d_in[13];
    const float* bi    = (const float*)d_in[14]; const float* bh    = (const float*)d_in[15];
    const float* W11   = (const float*)d_in[16]; const float* b11   = (const float*)d_in[17];
    const float* W12   = (const float*)d_in[18]; const float* b12   = (const float*)d_in[19];
    const float* W13   = (const float*)d_in[20]; const float* b13   = (const float*)d_in[21];
    const float* W21   = (const float*)d_in[22]; const float* b21   = (const float*)d_in[23];
    const float* W22   = (const float*)d_in[24]; const float* b22   = (const float*)d_in[25];
    const float* W23   = (const float*)d_in[26]; const float* b23   = (const float*)d_in[27];
    float* out = (float*)d_out;

    // workspace: total 10,478,592 B
    char* ws = (char*)d_ws;
    float* agg    = (float*)(ws);                       // 6,400,000 B
    u16*   x1b    = (u16*)(ws + 6400000);               // 3,200,000 B
    u16*   Bt2    = (u16*)(ws + 9600000);               //   532,480 B
    float* pooled = (float*)(ws + 10132480);            //   256,000 B
    u16*   Wib    = (u16*)(ws + 10388480);              //    24,576 B
    u16*   Whb    = (u16*)(ws + 10413056);              //    24,576 B
    u16*   Wrb    = (u16*)(ws + 10437632);              //     8,192 B
    u16*   W11b   = (u16*)(ws + 10445824);              //     8,192 B
    u16*   W12b   = (u16*)(ws + 10454016);              //     8,192 B
    u16*   W21b   = (u16*)(ws + 10462208);              //     8,192 B
    u16*   W22b   = (u16*)(ws + 10470400);              //     8,192 B

    hipLaunchKernelGGL(k_pre, dim3(1884), dim3(256), 0, stream,
                       x, W0, b0, x1b, We2, be2, agg, pooled, Bt2,
                       Wi, Wh, Wroot, Wib, Whb, Wrb,
                       W11, W12, W21, W22, W11b, W12b, W21b, W22b);
    hipLaunchKernelGGL(k_msg, dim3(782), dim3(512), 0, stream, ea, eidx, We1, be1, x1b, Bt2, agg);
    hipLaunchKernelGGL(k_gru, dim3(391), dim3(256), 0, stream, x1b, agg,
                       Wib, Whb, Wrb, bconv, bi, bh, batch, pooled);
    hipLaunchKernelGGL(k_heads, dim3(16), dim3(256), 0, stream, pooled,
                       W11b, b11, W12b, b12, W13, b13, W21b, b21, W22b, b22, W23, b23, out);
}